// Round 1
// baseline (149.811 us; speedup 1.0000x reference)
//
#include <hip/hip_runtime.h>
#include <math.h>

#define NT 4096
#define MODES 64
#define NB 32
#define NCI 64
#define NCO 64
#define ROWS 2048  // NB*NCI == NB*NCO

static __device__ __forceinline__ void rot(float& wr, float& wi, float sr, float si) {
  float nr = fmaf(wr, sr, -wi * si);
  float ni = fmaf(wr, si,  wi * sr);
  wr = nr; wi = ni;
}

// ---------------------------------------------------------------------------
// K1: CFT partials. xf[row,k] = (1/n) sum_t x[row,t] e^{-2pi i k t / 4096}
// grid = 512: 128 row-blocks (16 rows each) x 4 t-splits (1024 t each).
// 256 threads: k = tid&63, rg = tid>>6 -> 4 rows per thread.
// Output: xfp[ts][row][k] (complex), partial over the t-split.
// ---------------------------------------------------------------------------
__global__ __launch_bounds__(256) void cft_kernel(const float* __restrict__ x,
                                                  float2* __restrict__ xfp) {
  __shared__ float xs[16][256];  // [row_local][t_local]
  const int blk = blockIdx.x;
  const int rowblk = blk >> 2;   // 0..127
  const int ts = blk & 3;        // t-split 0..3
  const int row0 = rowblk * 16;
  const int tid = threadIdx.x;
  const int k = tid & 63;
  const int rg = tid >> 6;       // 0..3

  float ar[4] = {0.f, 0.f, 0.f, 0.f};
  float ai[4] = {0.f, 0.f, 0.f, 0.f};

  // per-t step twiddle e^{-2pi i k / 4096}
  float sr, si;
  sincosf(-6.283185307179586f * (float)k / 4096.0f, &si, &sr);

  const float4* x4 = (const float4*)x;

  for (int tc = 0; tc < 4; ++tc) {
    const int tbase = ts * 1024 + tc * 256;
    __syncthreads();
    {  // stage 16 rows x 256 t, coalesced float4 loads, LDS [row][t]
      const int c = tid & 63;
      const int r_ = tid >> 6;
#pragma unroll
      for (int rep = 0; rep < 4; ++rep) {
        const int rl = rep * 4 + r_;
        float4 v = x4[(size_t)(row0 + rl) * 1024 + (tbase >> 2) + c];
        ((float4*)&xs[rl][0])[c] = v;
      }
    }
    __syncthreads();
    // exact re-seed of the rotating twiddle at t = tbase (bounds drift to <=256 steps)
    float wr, wi;
    {
      const int mm = (k * tbase) & 4095;
      sincosf(-6.283185307179586f * (float)mm / 4096.0f, &wi, &wr);
    }
    for (int tl = 0; tl < 256; ++tl) {
#pragma unroll
      for (int r = 0; r < 4; ++r) {
        const float xv = xs[rg * 4 + r][tl];  // wave-uniform broadcast read
        ar[r] = fmaf(xv, wr, ar[r]);
        ai[r] = fmaf(xv, wi, ai[r]);
      }
      rot(wr, wi, sr, si);
    }
  }
  const float dt = 1.0f / 4096.0f;
#pragma unroll
  for (int r = 0; r < 4; ++r) {
    const int row = row0 + rg * 4 + r;
    xfp[((size_t)ts * ROWS + row) * MODES + k] = make_float2(ar[r] * dt, ai[r] * dt);
  }
}

// ---------------------------------------------------------------------------
// K2: sum the 4 CFT partials and apply the spectral mix:
//   yf[b,o,k] = sum_i xf[b,i,k] * (wr + i wi)[i,o,k]
// grid = 512: 32 b x 16 k-groups (4 k each). 256 threads: o = tid&63, kk = tid>>6.
// ---------------------------------------------------------------------------
__global__ __launch_bounds__(256) void mix_kernel(const float2* __restrict__ xfp,
                                                  const float* __restrict__ w_real,
                                                  const float* __restrict__ w_imag,
                                                  float2* __restrict__ yf) {
  __shared__ float2 xsh[64][4];  // [i][kk]
  const int b = blockIdx.x >> 4;
  const int kg = blockIdx.x & 15;
  const int tid = threadIdx.x;
  {
    const int i = tid >> 2;
    const int kk2 = tid & 3;
    float2 v = make_float2(0.f, 0.f);
#pragma unroll
    for (int s = 0; s < 4; ++s) {
      float2 p = xfp[((size_t)s * ROWS + b * NCI + i) * MODES + kg * 4 + kk2];
      v.x += p.x; v.y += p.y;
    }
    xsh[i][kk2] = v;
  }
  __syncthreads();
  const int o = tid & 63;
  const int kk = tid >> 6;
  const int k = kg * 4 + kk;
  float accr = 0.f, acci = 0.f;
  for (int i = 0; i < NCI; ++i) {
    const float2 xv = xsh[i][kk];  // broadcast
    const float wr = w_real[((size_t)i * NCO + o) * MODES + k];
    const float wi = w_imag[((size_t)i * NCO + o) * MODES + k];
    accr = fmaf(xv.x, wr, accr); accr = fmaf(-xv.y, wi, accr);
    acci = fmaf(xv.x, wi, acci); acci = fmaf(xv.y, wr, acci);
  }
  yf[((size_t)b * NCO + o) * MODES + k] = make_float2(accr, acci);
}

// ---------------------------------------------------------------------------
// K3: ICFT with the fftshift pairing folded in:
//   out[row,t] = (-1)^t * Re sum_k yf[row,k] e^{+2pi i k t / 4096}
// grid = 4096: 256 row-groups (8 rows) x 16 t-chunks (256 t).
// Each thread: one t, all 8 rows; rotate over k (4 VALU amortized over 8 rows).
// ---------------------------------------------------------------------------
__global__ __launch_bounds__(256) void icft_kernel(const float2* __restrict__ yf,
                                                   float* __restrict__ out) {
  __shared__ float2 ysh[8][64];  // [row_local][k]
  const int blk = blockIdx.x;
  const int rgrp = blk >> 4;
  const int tc = blk & 15;
  const int row0 = rgrp * 8;
  const int tid = threadIdx.x;
#pragma unroll
  for (int rep = 0; rep < 2; ++rep) {
    const int idx = rep * 256 + tid;
    const int rl = idx >> 6;
    const int kk = idx & 63;
    ysh[rl][kk] = yf[(size_t)(row0 + rl) * MODES + kk];
  }
  __syncthreads();
  const int t = tc * 256 + tid;
  float sr, si;
  sincosf(6.283185307179586f * (float)t / 4096.0f, &si, &sr);
  float wr = 1.0f, wi = 0.0f;  // e^{2pi i t k/4096} at k=0
  float acc[8] = {0.f, 0.f, 0.f, 0.f, 0.f, 0.f, 0.f, 0.f};
  for (int k = 0; k < MODES; ++k) {
#pragma unroll
    for (int r = 0; r < 8; ++r) {
      const float2 y = ysh[r][k];  // wave-uniform broadcast read
      acc[r] = fmaf(y.x, wr, acc[r]);
      acc[r] = fmaf(-y.y, wi, acc[r]);
    }
    rot(wr, wi, sr, si);
  }
  const float sgn = (t & 1) ? -1.0f : 1.0f;
#pragma unroll
  for (int r = 0; r < 8; ++r) {
    out[(size_t)(row0 + r) * NT + t] = sgn * acc[r];
  }
}

extern "C" void kernel_launch(void* const* d_in, const int* in_sizes, int n_in,
                              void* d_out, int out_size, void* d_ws, size_t ws_size,
                              hipStream_t stream) {
  const float* x      = (const float*)d_in[0];
  const float* w_real = (const float*)d_in[1];
  const float* w_imag = (const float*)d_in[2];
  float* out = (float*)d_out;

  // ws layout: xfp = 4 partials x 2048 rows x 64 modes complex = 4 MB
  //            yf  = 2048 rows x 64 modes complex              = 1 MB
  float2* xfp = (float2*)d_ws;
  float2* yf  = (float2*)((char*)d_ws + (size_t)4 * ROWS * MODES * sizeof(float2));

  cft_kernel<<<512, 256, 0, stream>>>(x, xfp);
  mix_kernel<<<512, 256, 0, stream>>>(xfp, w_real, w_imag, yf);
  icft_kernel<<<4096, 256, 0, stream>>>(yf, out);
}

// Round 2
// 122.385 us; speedup vs baseline: 1.2241x; 1.2241x over previous
//
#include <hip/hip_runtime.h>
#include <math.h>

#define NT 4096
#define Q 1024          // NT/4
#define MODES 64
#define ROWS 2048       // B*Ci == B*Co
#define TWO_PI 6.283185307179586f

static __device__ __forceinline__ void rotm(float& wr, float& wi, float sr, float si) {
  float nr = fmaf(wr, sr, -wi * si);
  float ni = fmaf(wr, si,  wi * sr);
  wr = nr; wi = ni;
}

// ---------------------------------------------------------------------------
// K1: folded CFT partials.
//   xf[row,k] = (1/4096) sum_t x[row,t] e^{-2pi i k t/4096}
// Fold t = tl + 1024 j:  e^{-2pi i k t/4096} = w_k(tl) * (-i)^{(k%4) j}
//   s(tl) = sum_j x[tl+1024j] (-i)^{cj}, uniform form with per-lane (p,qc,rc):
//     u = x0 + p*x2, v = x1 + p*x3, sr = u + qc*v, si = rc*v
//   c=0: p=+1 qc=+1 rc=0 ; c=1: p=-1 qc=0 rc=-1 ; c=2: p=+1 qc=-1 rc=0 ; c=3: p=-1 qc=0 rc=+1
// Thread: k in {k0, k0+16, k0+32, k0+48} (same k%4), 2 rows; 32 rows/block.
// Grid: 64 rowblocks x S t-splits. Partial sums to xfp[ts][row][k].
// ---------------------------------------------------------------------------
__global__ __launch_bounds__(256) void cft_kernel(const float* __restrict__ x,
                                                  float2* __restrict__ xfp, int S) {
  // [row][j][tl] with padded row stride 260 floats (65 float4) so the 4
  // distinct row-broadcast reads per wave hit distinct banks.
  __shared__ float4 xs4[32 * 65];   // 33280 B
  const int tid = threadIdx.x;
  const int k0 = tid & 15;
  const int rg = tid >> 4;          // 0..15 -> rows rg*2, rg*2+1
  const int C = Q / S;
  const int rowblk = (int)blockIdx.x / S;
  const int ts = (int)blockIdx.x % S;
  const int row0 = rowblk * 32;

  const int c = k0 & 3;
  const float p  = (c & 1) ? -1.f : 1.f;
  const float qc = (c == 0) ? 1.f : ((c == 2) ? -1.f : 0.f);
  const float rc = (c == 1) ? -1.f : ((c == 3) ? 1.f : 0.f);

  float str[4], sti[4];             // per-tl twiddle steps e^{-2pi i k/4096}
#pragma unroll
  for (int q = 0; q < 4; ++q) {
    const int k = k0 + 16 * q;
    sincosf(-TWO_PI * (float)k / (float)NT, &sti[q], &str[q]);
  }

  float ar[2][4] = {{0.f,0.f,0.f,0.f},{0.f,0.f,0.f,0.f}};
  float ai[2][4] = {{0.f,0.f,0.f,0.f},{0.f,0.f,0.f,0.f}};

  const float4* __restrict__ xg4 = (const float4*)x;
  const float* xsf = (const float*)xs4;

  for (int sub = 0; sub < C / 64; ++sub) {
    const int tl0 = ts * C + sub * 64;
    __syncthreads();
    // stage 32 rows x 4 j x 64 tl = 2048 float4; 8 per thread, coalesced.
#pragma unroll
    for (int it = 0; it < 8; ++it) {
      const int idx = tid + it * 256;
      const int tlf = idx & 15;
      const int j = (idx >> 4) & 3;
      const int row = idx >> 6;
      float4 v = xg4[(size_t)(row0 + row) * (NT / 4) + j * (Q / 4) + (tl0 >> 2) + tlf];
      xs4[row * 65 + j * 16 + tlf] = v;
    }
    __syncthreads();
    // exact integer-phase seed at tl0 for each k
    float wr[4], wi[4];
#pragma unroll
    for (int q = 0; q < 4; ++q) {
      const int k = k0 + 16 * q;
      const int ph = (k * tl0) & (NT - 1);
      sincosf(-TWO_PI * (float)ph / (float)NT, &wi[q], &wr[q]);
    }
    for (int tl = 0; tl < 64; ++tl) {
#pragma unroll
      for (int rr = 0; rr < 2; ++rr) {
        const int row = rg * 2 + rr;
        const float* bp = xsf + row * 260 + tl;
        const float x0 = bp[0], x1 = bp[64], x2 = bp[128], x3 = bp[192];
        const float u = fmaf(p, x2, x0);
        const float v = fmaf(p, x3, x1);
        const float sr = fmaf(qc, v, u);
        const float si = rc * v;
#pragma unroll
        for (int q = 0; q < 4; ++q) {
          ar[rr][q] = fmaf(sr, wr[q], ar[rr][q]);
          ar[rr][q] = fmaf(-si, wi[q], ar[rr][q]);
          ai[rr][q] = fmaf(sr, wi[q], ai[rr][q]);
          ai[rr][q] = fmaf(si, wr[q], ai[rr][q]);
        }
      }
#pragma unroll
      for (int q = 0; q < 4; ++q) rotm(wr[q], wi[q], str[q], sti[q]);
    }
  }
  const float dt = 1.0f / (float)NT;
#pragma unroll
  for (int rr = 0; rr < 2; ++rr) {
    const int row = row0 + rg * 2 + rr;
#pragma unroll
    for (int q = 0; q < 4; ++q) {
      xfp[((size_t)ts * ROWS + row) * MODES + k0 + 16 * q] =
          make_float2(ar[rr][q] * dt, ai[rr][q] * dt);
    }
  }
}

// ---------------------------------------------------------------------------
// K2: sum the S CFT partials and apply the spectral mix:
//   yf[b,o,k] = sum_i xf[b,i,k] * (wr + i wi)[i,o,k]
// grid = 512: 32 b x 16 k-groups (4 k each). 256 threads: o = tid&63, kk = tid>>6.
// ---------------------------------------------------------------------------
__global__ __launch_bounds__(256) void mix_kernel(const float2* __restrict__ xfp,
                                                  const float* __restrict__ w_real,
                                                  const float* __restrict__ w_imag,
                                                  float2* __restrict__ yf, int S) {
  __shared__ float2 xsh[64][4];  // [i][kk]
  const int b = blockIdx.x >> 4;
  const int kg = blockIdx.x & 15;
  const int tid = threadIdx.x;
  {
    const int i = tid >> 2;
    const int kk2 = tid & 3;
    float2 v = make_float2(0.f, 0.f);
    for (int s = 0; s < S; ++s) {
      float2 pp = xfp[((size_t)s * ROWS + b * 64 + i) * MODES + kg * 4 + kk2];
      v.x += pp.x; v.y += pp.y;
    }
    xsh[i][kk2] = v;
  }
  __syncthreads();
  const int o = tid & 63;
  const int kk = tid >> 6;
  const int k = kg * 4 + kk;
  float accr = 0.f, acci = 0.f;
#pragma unroll 8
  for (int i = 0; i < 64; ++i) {
    const float2 xv = xsh[i][kk];  // broadcast
    const float wr = w_real[((size_t)i * 64 + o) * MODES + k];
    const float wi = w_imag[((size_t)i * 64 + o) * MODES + k];
    accr = fmaf(xv.x, wr, accr); accr = fmaf(-xv.y, wi, accr);
    acci = fmaf(xv.x, wi, acci); acci = fmaf(xv.y, wr, acci);
  }
  yf[((size_t)b * 64 + o) * MODES + k] = make_float2(accr, acci);
}

// ---------------------------------------------------------------------------
// K3: folded ICFT with the fftshift pairing:
//   out[row,t] = (-1)^t Re sum_k yf[row,k] e^{+2pi i k t/4096}
// Fold t = tl + 1024 j:  e^{...} picks up i^{(k%4) j}. Accumulate per-class
//   G_c = sum_{k=c mod 4} y_k w_k(tl)  (G0i, G2i never needed), combine:
//   o0 = (G0r+G2r)+(G1r+G3r); o2 = (G0r+G2r)-(G1r+G3r)
//   o1 = (G0r-G2r)+(G3i-G1i); o3 = (G0r-G2r)-(G3i-G1i)
// grid = 1024: 256 rowgroups (8 rows) x 4 tl-chunks (256 each).
// ---------------------------------------------------------------------------
__global__ __launch_bounds__(256) void icft_kernel(const float2* __restrict__ yf,
                                                   float* __restrict__ out) {
  __shared__ float4 ysh4[8][32];  // [row][k-pair], 2 complex per float4
  const int rgrp = blockIdx.x >> 2;
  const int tc = blockIdx.x & 3;
  const int row0 = rgrp * 8;
  const int tid = threadIdx.x;
  {
    const int rl = tid >> 5;    // 0..7
    const int kp = tid & 31;    // 0..31
    ysh4[rl][kp] = ((const float4*)yf)[(size_t)(row0 + rl) * 32 + kp];
  }
  __syncthreads();
  const int tl = tc * 256 + tid;
  float stepr, stepi;
  sincosf(TWO_PI * (float)tl / (float)NT, &stepi, &stepr);
  float w0r = 1.f, w0i = 0.f;   // e^{2pi i tl k/4096} at k=0
  float Gr0[8] = {}, Gr1[8] = {}, Gr2[8] = {}, Gr3[8] = {}, Gi1[8] = {}, Gi3[8] = {};
  for (int qd = 0; qd < 16; ++qd) {   // k = 4*qd + c
    const float w1r = fmaf(w0r, stepr, -w0i * stepi);
    const float w1i = fmaf(w0r, stepi,  w0i * stepr);
    const float w2r = fmaf(w1r, stepr, -w1i * stepi);
    const float w2i = fmaf(w1r, stepi,  w1i * stepr);
    const float w3r = fmaf(w2r, stepr, -w2i * stepi);
    const float w3i = fmaf(w2r, stepi,  w2i * stepr);
#pragma unroll
    for (int r = 0; r < 8; ++r) {
      const float4 ya = ysh4[r][2 * qd];      // broadcast: y_{4qd}, y_{4qd+1}
      const float4 yb = ysh4[r][2 * qd + 1];  // y_{4qd+2}, y_{4qd+3}
      Gr0[r] = fmaf(ya.x, w0r, Gr0[r]); Gr0[r] = fmaf(-ya.y, w0i, Gr0[r]);
      Gr1[r] = fmaf(ya.z, w1r, Gr1[r]); Gr1[r] = fmaf(-ya.w, w1i, Gr1[r]);
      Gi1[r] = fmaf(ya.z, w1i, Gi1[r]); Gi1[r] = fmaf( ya.w, w1r, Gi1[r]);
      Gr2[r] = fmaf(yb.x, w2r, Gr2[r]); Gr2[r] = fmaf(-yb.y, w2i, Gr2[r]);
      Gr3[r] = fmaf(yb.z, w3r, Gr3[r]); Gr3[r] = fmaf(-yb.w, w3i, Gr3[r]);
      Gi3[r] = fmaf(yb.z, w3i, Gi3[r]); Gi3[r] = fmaf( yb.w, w3r, Gi3[r]);
    }
    const float nr = fmaf(w3r, stepr, -w3i * stepi);
    const float ni = fmaf(w3r, stepi,  w3i * stepr);
    w0r = nr; w0i = ni;
  }
  const float sgn = (tid & 1) ? -1.f : 1.f;  // (-1)^t, t parity == tid parity
#pragma unroll
  for (int r = 0; r < 8; ++r) {
    const float bs = Gr0[r] + Gr2[r];
    const float bd = Gr1[r] + Gr3[r];
    const float as = Gr0[r] - Gr2[r];
    const float ad = Gi3[r] - Gi1[r];
    float* op = out + (size_t)(row0 + r) * NT + tl;
    op[0]     = sgn * (bs + bd);
    op[Q]     = sgn * (as + ad);
    op[2 * Q] = sgn * (bs - bd);
    op[3 * Q] = sgn * (as - ad);
  }
}

extern "C" void kernel_launch(void* const* d_in, const int* in_sizes, int n_in,
                              void* d_out, int out_size, void* d_ws, size_t ws_size,
                              hipStream_t stream) {
  const float* x      = (const float*)d_in[0];
  const float* w_real = (const float*)d_in[1];
  const float* w_imag = (const float*)d_in[2];
  float* out = (float*)d_out;

  // Choose t-split factor S from available workspace (deterministic).
  // Need (S+1) * 2048*64*8 bytes. S=4 matches round 1's proven footprint.
  int S = 16;
  while (S > 4 && (size_t)(S + 1) * ROWS * MODES * sizeof(float2) > ws_size) S >>= 1;

  float2* xfp = (float2*)d_ws;
  float2* yf  = (float2*)((char*)d_ws + (size_t)S * ROWS * MODES * sizeof(float2));

  cft_kernel<<<64 * S, 256, 0, stream>>>(x, xfp, S);
  mix_kernel<<<512, 256, 0, stream>>>(xfp, w_real, w_imag, yf, S);
  icft_kernel<<<1024, 256, 0, stream>>>(yf, out);
}

// Round 3
// 79.816 us; speedup vs baseline: 1.8769x; 1.5333x over previous
//
#include <hip/hip_runtime.h>
#include <math.h>

#define NT 4096
#define Q 1024          // NT/4
#define MODES 64
#define ROWS 2048       // B*Ci == B*Co
#define TWO_PI 6.283185307179586f

static __device__ __forceinline__ void rotm(float& wr, float& wi, float sr, float si) {
  float nr = fmaf(wr, sr, -wi * si);
  float ni = fmaf(wr, si,  wi * sr);
  wr = nr; wi = ni;
}

// ---------------------------------------------------------------------------
// K1: folded CFT partials (unchanged from round 2).
//   xf[row,k] = (1/4096) sum_t x[row,t] e^{-2pi i k t/4096}
// Fold t = tl + 1024 j; thread handles k in {k0,k0+16,k0+32,k0+48}, 2 rows.
// Grid: 64 rowblocks x S t-splits -> xfp[ts][row][k].
// ---------------------------------------------------------------------------
__global__ __launch_bounds__(256) void cft_kernel(const float* __restrict__ x,
                                                  float2* __restrict__ xfp, int S) {
  __shared__ float4 xs4[32 * 65];   // [row][j][tl], padded row stride 260 floats
  const int tid = threadIdx.x;
  const int k0 = tid & 15;
  const int rg = tid >> 4;          // rows rg*2, rg*2+1
  const int C = Q / S;
  const int rowblk = (int)blockIdx.x / S;
  const int ts = (int)blockIdx.x % S;
  const int row0 = rowblk * 32;

  const int c = k0 & 3;
  const float p  = (c & 1) ? -1.f : 1.f;
  const float qc = (c == 0) ? 1.f : ((c == 2) ? -1.f : 0.f);
  const float rc = (c == 1) ? -1.f : ((c == 3) ? 1.f : 0.f);

  float str[4], sti[4];
#pragma unroll
  for (int q = 0; q < 4; ++q) {
    const int k = k0 + 16 * q;
    sincosf(-TWO_PI * (float)k / (float)NT, &sti[q], &str[q]);
  }

  float ar[2][4] = {{0.f,0.f,0.f,0.f},{0.f,0.f,0.f,0.f}};
  float ai[2][4] = {{0.f,0.f,0.f,0.f},{0.f,0.f,0.f,0.f}};

  const float4* __restrict__ xg4 = (const float4*)x;
  const float* xsf = (const float*)xs4;

  for (int sub = 0; sub < C / 64; ++sub) {
    const int tl0 = ts * C + sub * 64;
    __syncthreads();
#pragma unroll
    for (int it = 0; it < 8; ++it) {
      const int idx = tid + it * 256;
      const int tlf = idx & 15;
      const int j = (idx >> 4) & 3;
      const int row = idx >> 6;
      float4 v = xg4[(size_t)(row0 + row) * (NT / 4) + j * (Q / 4) + (tl0 >> 2) + tlf];
      xs4[row * 65 + j * 16 + tlf] = v;
    }
    __syncthreads();
    float wr[4], wi[4];
#pragma unroll
    for (int q = 0; q < 4; ++q) {
      const int k = k0 + 16 * q;
      const int ph = (k * tl0) & (NT - 1);
      sincosf(-TWO_PI * (float)ph / (float)NT, &wi[q], &wr[q]);
    }
    for (int tl = 0; tl < 64; ++tl) {
#pragma unroll
      for (int rr = 0; rr < 2; ++rr) {
        const int row = rg * 2 + rr;
        const float* bp = xsf + row * 260 + tl;
        const float x0 = bp[0], x1 = bp[64], x2 = bp[128], x3 = bp[192];
        const float u = fmaf(p, x2, x0);
        const float v = fmaf(p, x3, x1);
        const float sr = fmaf(qc, v, u);
        const float si = rc * v;
#pragma unroll
        for (int q = 0; q < 4; ++q) {
          ar[rr][q] = fmaf(sr, wr[q], ar[rr][q]);
          ar[rr][q] = fmaf(-si, wi[q], ar[rr][q]);
          ai[rr][q] = fmaf(sr, wi[q], ai[rr][q]);
          ai[rr][q] = fmaf(si, wr[q], ai[rr][q]);
        }
      }
#pragma unroll
      for (int q = 0; q < 4; ++q) rotm(wr[q], wi[q], str[q], sti[q]);
    }
  }
  const float dt = 1.0f / (float)NT;
#pragma unroll
  for (int rr = 0; rr < 2; ++rr) {
    const int row = row0 + rg * 2 + rr;
#pragma unroll
    for (int q = 0; q < 4; ++q) {
      xfp[((size_t)ts * ROWS + row) * MODES + k0 + 16 * q] =
          make_float2(ar[rr][q] * dt, ai[rr][q] * dt);
    }
  }
}

// ---------------------------------------------------------------------------
// K2a: transpose w into w_t[k][i*64+o] so the mix reads coalesced.
// Treat w as A[4096][64]; 64x64 LDS-tiled transpose. 128 blocks (64 x {re,im}).
// ---------------------------------------------------------------------------
__global__ __launch_bounds__(256) void transpose_w(const float* __restrict__ w_real,
                                                   const float* __restrict__ w_imag,
                                                   float* __restrict__ wrt,
                                                   float* __restrict__ wit) {
  __shared__ float tile[64][65];
  const int sel = blockIdx.x >> 6;
  const int io0 = (blockIdx.x & 63) * 64;
  const float* __restrict__ src = sel ? w_imag : w_real;
  float* __restrict__ dst = sel ? wit : wrt;
  const int tid = threadIdx.x;
#pragma unroll
  for (int j = 0; j < 4; ++j) {
    const int idx = tid + j * 256;
    const int r = idx >> 4;
    const int kq = idx & 15;
    float4 v = ((const float4*)src)[(size_t)(io0 + r) * 16 + kq];
    tile[r][4 * kq + 0] = v.x; tile[r][4 * kq + 1] = v.y;
    tile[r][4 * kq + 2] = v.z; tile[r][4 * kq + 3] = v.w;
  }
  __syncthreads();
#pragma unroll
  for (int j = 0; j < 16; ++j) {
    const int idx = tid + j * 256;
    const int k = idx >> 6;
    const int r = idx & 63;
    dst[(size_t)k * 4096 + io0 + r] = tile[r][k];
  }
}

// ---------------------------------------------------------------------------
// K2b: reduce the S CFT partials (coalesced) + 64x64 transpose -> xf_t[k][row].
// 32 blocks of 64 rows.
// ---------------------------------------------------------------------------
__global__ __launch_bounds__(256) void reduce_t(const float4* __restrict__ xfp4,
                                                float2* __restrict__ xf_t, int S) {
  __shared__ float2 tile[64][65];
  const int row0 = (int)blockIdx.x * 64;
  const int tid = threadIdx.x;
  float4 acc[8];
#pragma unroll
  for (int j = 0; j < 8; ++j) acc[j] = make_float4(0.f, 0.f, 0.f, 0.f);
  for (int s = 0; s < S; ++s) {
    const float4* __restrict__ p = xfp4 + ((size_t)s * ROWS + row0) * 32;
#pragma unroll
    for (int j = 0; j < 8; ++j) {
      float4 v = p[tid + 256 * j];
      acc[j].x += v.x; acc[j].y += v.y; acc[j].z += v.z; acc[j].w += v.w;
    }
  }
#pragma unroll
  for (int j = 0; j < 8; ++j) {
    const int idx = tid + 256 * j;
    const int r = idx >> 5;
    const int kp = idx & 31;
    tile[r][2 * kp]     = make_float2(acc[j].x, acc[j].y);
    tile[r][2 * kp + 1] = make_float2(acc[j].z, acc[j].w);
  }
  __syncthreads();
#pragma unroll
  for (int j = 0; j < 16; ++j) {
    const int idx = tid + 256 * j;
    const int k = idx >> 6;
    const int r = idx & 63;
    xf_t[(size_t)k * ROWS + row0 + r] = tile[r][k];
  }
}

// ---------------------------------------------------------------------------
// K2c: spectral mix, per-k complex GEMM entirely from LDS.
//   yf[b,o,k] = sum_i xf[b,i,k] * W[i,o,k]
// grid = 128: k x b-half. LDS: W k-slice (interleaved, 32 KB) + X half-slice (8 KB).
// Thread: o = tid&63, 4 b's. Writes yf_t[k][b*64+o] coalesced.
// ---------------------------------------------------------------------------
__global__ __launch_bounds__(256) void mix_kernel(const float* __restrict__ wrt,
                                                  const float* __restrict__ wit,
                                                  const float2* __restrict__ xf_t,
                                                  float2* __restrict__ yf_t) {
  __shared__ float2 wsc[4096];
  __shared__ float2 xsh[1024];
  const int k = blockIdx.x >> 1;
  const int bh = blockIdx.x & 1;
  const int tid = threadIdx.x;
#pragma unroll
  for (int j = 0; j < 4; ++j) {
    const int idx = tid + 256 * j;
    float4 vr = ((const float4*)(wrt + (size_t)k * 4096))[idx];
    float4 vi = ((const float4*)(wit + (size_t)k * 4096))[idx];
    wsc[4 * idx + 0] = make_float2(vr.x, vi.x);
    wsc[4 * idx + 1] = make_float2(vr.y, vi.y);
    wsc[4 * idx + 2] = make_float2(vr.z, vi.z);
    wsc[4 * idx + 3] = make_float2(vr.w, vi.w);
  }
#pragma unroll
  for (int j = 0; j < 2; ++j) {
    ((float4*)xsh)[tid + 256 * j] =
        ((const float4*)(xf_t + (size_t)k * ROWS + bh * 1024))[tid + 256 * j];
  }
  __syncthreads();
  const int o = tid & 63;
  const int bq = tid >> 6;
  float ar[4] = {0.f, 0.f, 0.f, 0.f};
  float ai[4] = {0.f, 0.f, 0.f, 0.f};
#pragma unroll 4
  for (int i = 0; i < 64; ++i) {
    const float2 w = wsc[i * 64 + o];
#pragma unroll
    for (int jb = 0; jb < 4; ++jb) {
      const float2 xv = xsh[(bq * 4 + jb) * 64 + i];  // broadcast
      ar[jb] = fmaf(xv.x, w.x, ar[jb]); ar[jb] = fmaf(-xv.y, w.y, ar[jb]);
      ai[jb] = fmaf(xv.x, w.y, ai[jb]); ai[jb] = fmaf( xv.y, w.x, ai[jb]);
    }
  }
#pragma unroll
  for (int jb = 0; jb < 4; ++jb) {
    yf_t[(size_t)k * ROWS + bh * 1024 + (bq * 4 + jb) * 64 + o] =
        make_float2(ar[jb], ai[jb]);
  }
}

// ---------------------------------------------------------------------------
// K3: folded ICFT with fftshift pairing (math unchanged); staging from yf_t.
//   out[row,t] = (-1)^t Re sum_k yf[row,k] e^{+2pi i k t/4096}
// grid = 1024: 256 rowgroups (8 rows) x 4 tl-chunks (256 each).
// ---------------------------------------------------------------------------
__global__ __launch_bounds__(256) void icft_kernel(const float2* __restrict__ yf_t,
                                                   float* __restrict__ out) {
  __shared__ float2 ysh[8][66];
  const int rgrp = blockIdx.x >> 2;
  const int tc = blockIdx.x & 3;
  const int row0 = rgrp * 8;
  const int tid = threadIdx.x;
#pragma unroll
  for (int j = 0; j < 2; ++j) {
    const int kk = (tid >> 3) + 32 * j;
    const int rl = tid & 7;
    ysh[rl][kk] = yf_t[(size_t)kk * ROWS + row0 + rl];
  }
  __syncthreads();
  const int tl = tc * 256 + tid;
  float stepr, stepi;
  sincosf(TWO_PI * (float)tl / (float)NT, &stepi, &stepr);
  float w0r = 1.f, w0i = 0.f;
  float Gr0[8] = {}, Gr1[8] = {}, Gr2[8] = {}, Gr3[8] = {}, Gi1[8] = {}, Gi3[8] = {};
  for (int qd = 0; qd < 16; ++qd) {
    const float w1r = fmaf(w0r, stepr, -w0i * stepi);
    const float w1i = fmaf(w0r, stepi,  w0i * stepr);
    const float w2r = fmaf(w1r, stepr, -w1i * stepi);
    const float w2i = fmaf(w1r, stepi,  w1i * stepr);
    const float w3r = fmaf(w2r, stepr, -w2i * stepi);
    const float w3i = fmaf(w2r, stepi,  w2i * stepr);
#pragma unroll
    for (int r = 0; r < 8; ++r) {
      const float2 y0 = ysh[r][4 * qd + 0];
      const float2 y1 = ysh[r][4 * qd + 1];
      const float2 y2 = ysh[r][4 * qd + 2];
      const float2 y3 = ysh[r][4 * qd + 3];
      Gr0[r] = fmaf(y0.x, w0r, Gr0[r]); Gr0[r] = fmaf(-y0.y, w0i, Gr0[r]);
      Gr1[r] = fmaf(y1.x, w1r, Gr1[r]); Gr1[r] = fmaf(-y1.y, w1i, Gr1[r]);
      Gi1[r] = fmaf(y1.x, w1i, Gi1[r]); Gi1[r] = fmaf( y1.y, w1r, Gi1[r]);
      Gr2[r] = fmaf(y2.x, w2r, Gr2[r]); Gr2[r] = fmaf(-y2.y, w2i, Gr2[r]);
      Gr3[r] = fmaf(y3.x, w3r, Gr3[r]); Gr3[r] = fmaf(-y3.y, w3i, Gr3[r]);
      Gi3[r] = fmaf(y3.x, w3i, Gi3[r]); Gi3[r] = fmaf( y3.y, w3r, Gi3[r]);
    }
    const float nr = fmaf(w3r, stepr, -w3i * stepi);
    const float ni = fmaf(w3r, stepi,  w3i * stepr);
    w0r = nr; w0i = ni;
  }
  const float sgn = (tid & 1) ? -1.f : 1.f;
#pragma unroll
  for (int r = 0; r < 8; ++r) {
    const float bs = Gr0[r] + Gr2[r];
    const float bd = Gr1[r] + Gr3[r];
    const float as = Gr0[r] - Gr2[r];
    const float ad = Gi3[r] - Gi1[r];
    float* op = out + (size_t)(row0 + r) * NT + tl;
    op[0]     = sgn * (bs + bd);
    op[Q]     = sgn * (as + ad);
    op[2 * Q] = sgn * (bs - bd);
    op[3 * Q] = sgn * (as - ad);
  }
}

extern "C" void kernel_launch(void* const* d_in, const int* in_sizes, int n_in,
                              void* d_out, int out_size, void* d_ws, size_t ws_size,
                              hipStream_t stream) {
  const float* x      = (const float*)d_in[0];
  const float* w_real = (const float*)d_in[1];
  const float* w_imag = (const float*)d_in[2];
  float* out = (float*)d_out;

  const size_t MB = (size_t)ROWS * MODES * sizeof(float2);  // 1 MiB units
  int S = 16;
  while (S > 4 && (size_t)(S + 4) * MB > ws_size) S >>= 1;

  char* wsp = (char*)d_ws;
  float2* xfp  = (float2*)wsp;                    // S MB
  float2* xf_t = (float2*)(wsp + (size_t)S * MB); // 1 MB
  float2* yf_t = (float2*)(wsp + (size_t)(S + 1) * MB);
  float*  wrt  = (float*)(wsp + (size_t)(S + 2) * MB);
  float*  wit  = (float*)(wsp + (size_t)(S + 3) * MB);

  transpose_w<<<128, 256, 0, stream>>>(w_real, w_imag, wrt, wit);
  cft_kernel<<<64 * S, 256, 0, stream>>>(x, xfp, S);
  reduce_t<<<32, 256, 0, stream>>>((const float4*)xfp, xf_t, S);
  mix_kernel<<<128, 256, 0, stream>>>(wrt, wit, xf_t, yf_t);
  icft_kernel<<<1024, 256, 0, stream>>>(yf_t, out);
}

// Round 4
// 52.597 us; speedup vs baseline: 2.8483x; 1.5175x over previous
//
#include <hip/hip_runtime.h>
#include <math.h>

#define NT 4096
#define MODES 64
#define ROWS 2048       // B*Ci == B*Co
#define TWO_PI 6.283185307179586f
#define PI_F 3.14159265358979f

static __device__ __forceinline__ void rotm(float& wr, float& wi, float sr, float si) {
  float nr = fmaf(wr, sr, -wi * si);
  float ni = fmaf(wr, si,  wi * sr);
  wr = nr; wi = ni;
}

// ---------------------------------------------------------------------------
// K1: 8-fold CFT partials.
//   xf[row,k] = (1/4096) sum_t x[row,t] e^{-2pi i k t/4096}
// Fold t = tl + 512 j (j=0..7), tl in [0,512):
//   e^{-2pi i k t/4096} = w_k(tl) * e^{-i pi k j/4}
//   s_c(tl) = E_c + w^c * O_c,  c = k mod 8, w = e^{-i pi/4}
//   E_c = 4-fold combo (class c mod 4) on x[tl+1024m] (even j),
//   O_c = same on x[tl+512+1024m] (odd j).
// Thread: k in {k0,k0+16,k0+32,k0+48} (share k mod 8 = c), 2 rows; 32 rows/blk.
// Twiddles: two chains (even/odd tl) stepping by step^2, re-seeded per 32-tl.
// Grid: 64 rowblocks x S tl-splits -> xfp[ts][row][k].
// ---------------------------------------------------------------------------
__global__ __launch_bounds__(256) void cft_kernel(const float* __restrict__ x,
                                                  float2* __restrict__ xfp, int S) {
  __shared__ float4 xs4[32 * 65];   // [row][j(8)][tlf4(8)], row stride 260 floats
  const int tid = threadIdx.x;
  const int k0 = tid & 15;
  const int rg = tid >> 4;          // rows rg*2, rg*2+1
  const int C = 512 / S;            // tl per split (32 when S=16)
  const int rowblk = (int)blockIdx.x / S;
  const int ts = (int)blockIdx.x % S;
  const int row0 = rowblk * 32;

  const int c4 = k0 & 3;
  const float p  = (c4 & 1) ? -1.f : 1.f;
  const float qc = (c4 == 0) ? 1.f : ((c4 == 2) ? -1.f : 0.f);
  const float rc = (c4 == 1) ? -1.f : ((c4 == 3) ? 1.f : 0.f);
  const int c8 = k0 & 7;
  float Aw, Bw;   // Aw = cos(pi c/4), Bw = -sin(pi c/4)
  sincosf(-PI_F * (float)c8 * 0.25f, &Bw, &Aw);

  float st2r[4], st2i[4];           // step^2 = e^{-2pi i (2k)/4096}
#pragma unroll
  for (int q = 0; q < 4; ++q) {
    const int k = k0 + 16 * q;
    sincosf(-TWO_PI * (float)(2 * k) / (float)NT, &st2i[q], &st2r[q]);
  }

  float ar[2][4] = {{0.f,0.f,0.f,0.f},{0.f,0.f,0.f,0.f}};
  float ai[2][4] = {{0.f,0.f,0.f,0.f},{0.f,0.f,0.f,0.f}};

  const float4* __restrict__ xg4 = (const float4*)x;
  const float* xsf = (const float*)xs4;

  for (int sub = 0; sub < C / 32; ++sub) {
    const int tl0 = ts * C + sub * 32;
    __syncthreads();
    // stage 32 rows x 8 j x 32 tl = 2048 float4; 8 per thread, coalesced.
#pragma unroll
    for (int it = 0; it < 8; ++it) {
      const int idx = tid + it * 256;
      const int tlf = idx & 7;
      const int j = (idx >> 3) & 7;
      const int row = idx >> 6;
      float4 v = xg4[(size_t)(row0 + row) * (NT / 4) + j * 128 + (tl0 >> 2) + tlf];
      xs4[row * 65 + j * 8 + tlf] = v;
    }
    __syncthreads();
    // exact integer-phase seeds: chain A at tl0 (even offsets), B at tl0+1 (odd)
    float wAr[4], wAi[4], wBr[4], wBi[4];
#pragma unroll
    for (int q = 0; q < 4; ++q) {
      const int k = k0 + 16 * q;
      const int phA = (k * tl0) & (NT - 1);
      const int phB = (k * (tl0 + 1)) & (NT - 1);
      sincosf(-TWO_PI * (float)phA / (float)NT, &wAi[q], &wAr[q]);
      sincosf(-TWO_PI * (float)phB / (float)NT, &wBi[q], &wBr[q]);
    }
    for (int tt = 0; tt < 16; ++tt) {
#pragma unroll
      for (int par = 0; par < 2; ++par) {
        const int tl = 2 * tt + par;
        const float* wr = par ? wBr : wAr;
        const float* wi = par ? wBi : wAi;
#pragma unroll
        for (int rr = 0; rr < 2; ++rr) {
          const int row = rg * 2 + rr;
          const float* bp = xsf + row * 260 + tl;
          const float x0 = bp[0],   x1 = bp[32],  x2 = bp[64],  x3 = bp[96];
          const float x4 = bp[128], x5 = bp[160], x6 = bp[192], x7 = bp[224];
          // E on even j, O on odd j (4-fold class c4 each)
          const float ue = fmaf(p, x4, x0), ve = fmaf(p, x6, x2);
          const float Er = fmaf(qc, ve, ue), Ei = rc * ve;
          const float uo = fmaf(p, x5, x1), vo = fmaf(p, x7, x3);
          const float Or_ = fmaf(qc, vo, uo), Oi_ = rc * vo;
          float sr = fmaf(Aw, Or_, Er); sr = fmaf(-Bw, Oi_, sr);
          float si = fmaf(Aw, Oi_, Ei); si = fmaf( Bw, Or_, si);
#pragma unroll
          for (int q = 0; q < 4; ++q) {
            ar[rr][q] = fmaf(sr, wr[q], ar[rr][q]);
            ar[rr][q] = fmaf(-si, wi[q], ar[rr][q]);
            ai[rr][q] = fmaf(sr, wi[q], ai[rr][q]);
            ai[rr][q] = fmaf(si, wr[q], ai[rr][q]);
          }
        }
      }
#pragma unroll
      for (int q = 0; q < 4; ++q) {
        rotm(wAr[q], wAi[q], st2r[q], st2i[q]);
        rotm(wBr[q], wBi[q], st2r[q], st2i[q]);
      }
    }
  }
  const float dt = 1.0f / (float)NT;
#pragma unroll
  for (int rr = 0; rr < 2; ++rr) {
    const int row = row0 + rg * 2 + rr;
#pragma unroll
    for (int q = 0; q < 4; ++q) {
      xfp[((size_t)ts * ROWS + row) * MODES + k0 + 16 * q] =
          make_float2(ar[rr][q] * dt, ai[rr][q] * dt);
    }
  }
}

// ---------------------------------------------------------------------------
// K2: fused {transpose_w | reduce partials + transpose}.
// blocks 0..127:   w -> w_t[k][i*64+o]  (64x64 LDS-tiled transpose x {re,im})
// blocks 128..383: sum S partials for 8 rows (coalesced float4), 8x64
//                  transpose -> xf_t[k][row]
// ---------------------------------------------------------------------------
__global__ __launch_bounds__(256) void wt_reduce_kernel(
    const float* __restrict__ w_real, const float* __restrict__ w_imag,
    float* __restrict__ wrt, float* __restrict__ wit,
    const float4* __restrict__ xfp4, float2* __restrict__ xf_t, int S) {
  __shared__ float tile[64][65];
  __shared__ float2 rtile[8][65];
  const int tid = threadIdx.x;
  if (blockIdx.x < 128) {
    const int sel = blockIdx.x >> 6;
    const int io0 = ((int)blockIdx.x & 63) * 64;
    const float* __restrict__ src = sel ? w_imag : w_real;
    float* __restrict__ dst = sel ? wit : wrt;
#pragma unroll
    for (int j = 0; j < 4; ++j) {
      const int idx = tid + j * 256;
      const int r = idx >> 4;
      const int kq = idx & 15;
      float4 v = ((const float4*)src)[(size_t)(io0 + r) * 16 + kq];
      tile[r][4 * kq + 0] = v.x; tile[r][4 * kq + 1] = v.y;
      tile[r][4 * kq + 2] = v.z; tile[r][4 * kq + 3] = v.w;
    }
    __syncthreads();
#pragma unroll
    for (int j = 0; j < 16; ++j) {
      const int idx = tid + j * 256;
      const int k = idx >> 6;
      const int r = idx & 63;
      dst[(size_t)k * 4096 + io0 + r] = tile[r][k];
    }
  } else {
    const int blk = (int)blockIdx.x - 128;  // 0..255
    const int row0 = blk * 8;
    float4 acc = make_float4(0.f, 0.f, 0.f, 0.f);
    for (int s = 0; s < S; ++s) {
      float4 v = xfp4[((size_t)s * ROWS + row0) * 32 + tid];
      acc.x += v.x; acc.y += v.y; acc.z += v.z; acc.w += v.w;
    }
    const int r = tid >> 5;
    const int kp = tid & 31;
    rtile[r][2 * kp]     = make_float2(acc.x, acc.y);
    rtile[r][2 * kp + 1] = make_float2(acc.z, acc.w);
    __syncthreads();
#pragma unroll
    for (int jj = 0; jj < 2; ++jj) {
      const int e = tid + 256 * jj;
      const int k = e >> 3;
      const int rr = e & 7;
      xf_t[(size_t)k * ROWS + row0 + rr] = rtile[rr][k];
    }
  }
}

// ---------------------------------------------------------------------------
// K3: spectral mix, per-k complex GEMM entirely from LDS (unchanged).
//   yf[b,o,k] = sum_i xf[b,i,k] * W[i,o,k]
// ---------------------------------------------------------------------------
__global__ __launch_bounds__(256) void mix_kernel(const float* __restrict__ wrt,
                                                  const float* __restrict__ wit,
                                                  const float2* __restrict__ xf_t,
                                                  float2* __restrict__ yf_t) {
  __shared__ float2 wsc[4096];
  __shared__ float2 xsh[1024];
  const int k = blockIdx.x >> 1;
  const int bh = blockIdx.x & 1;
  const int tid = threadIdx.x;
#pragma unroll
  for (int j = 0; j < 4; ++j) {
    const int idx = tid + 256 * j;
    float4 vr = ((const float4*)(wrt + (size_t)k * 4096))[idx];
    float4 vi = ((const float4*)(wit + (size_t)k * 4096))[idx];
    wsc[4 * idx + 0] = make_float2(vr.x, vi.x);
    wsc[4 * idx + 1] = make_float2(vr.y, vi.y);
    wsc[4 * idx + 2] = make_float2(vr.z, vi.z);
    wsc[4 * idx + 3] = make_float2(vr.w, vi.w);
  }
#pragma unroll
  for (int j = 0; j < 2; ++j) {
    ((float4*)xsh)[tid + 256 * j] =
        ((const float4*)(xf_t + (size_t)k * ROWS + bh * 1024))[tid + 256 * j];
  }
  __syncthreads();
  const int o = tid & 63;
  const int bq = tid >> 6;
  float ar[4] = {0.f, 0.f, 0.f, 0.f};
  float ai[4] = {0.f, 0.f, 0.f, 0.f};
#pragma unroll 4
  for (int i = 0; i < 64; ++i) {
    const float2 w = wsc[i * 64 + o];
#pragma unroll
    for (int jb = 0; jb < 4; ++jb) {
      const float2 xv = xsh[(bq * 4 + jb) * 64 + i];  // broadcast
      ar[jb] = fmaf(xv.x, w.x, ar[jb]); ar[jb] = fmaf(-xv.y, w.y, ar[jb]);
      ai[jb] = fmaf(xv.x, w.y, ai[jb]); ai[jb] = fmaf( xv.y, w.x, ai[jb]);
    }
  }
#pragma unroll
  for (int jb = 0; jb < 4; ++jb) {
    yf_t[(size_t)k * ROWS + bh * 1024 + (bq * 4 + jb) * 64 + o] =
        make_float2(ar[jb], ai[jb]);
  }
}

// ---------------------------------------------------------------------------
// K4: 8-fold ICFT with fftshift pairing:
//   out[row,t] = (-1)^t Re sum_k yf[row,k] e^{+2pi i k t/4096}
// Fold t = tl + 512 j: phase picks up e^{+i pi c j/4}, c = k mod 8.
// Accumulate G_c = sum_{k=c mod 8} y_k w_k(tl) (Gi skipped for c=0,4), then
// 8-point combine (verified subsum identities). 4 rows/thread.
// grid = 1024: 512 rowgroups (4 rows) x 2 tl-chunks (256 each).
// ---------------------------------------------------------------------------
__global__ __launch_bounds__(256) void icft_kernel(const float2* __restrict__ yf_t,
                                                   float* __restrict__ out) {
  __shared__ float2 ysh[4][66];
  const int rgrp = blockIdx.x >> 1;
  const int tc = blockIdx.x & 1;
  const int row0 = rgrp * 4;
  const int tid = threadIdx.x;
  {
    const int k = tid >> 2;
    const int r = tid & 3;
    ysh[r][k] = yf_t[(size_t)k * ROWS + row0 + r];
  }
  __syncthreads();
  const int tl = tc * 256 + tid;
  float stepr, stepi;
  sincosf(TWO_PI * (float)tl / (float)NT, &stepi, &stepr);
  float wr = 1.f, wi = 0.f;   // e^{+2pi i k tl/4096} at k=0
  float Gr[8][4] = {{0.f}};
  float Gi[8][4] = {{0.f}};   // [0],[4] unused -> dead after unroll
  for (int m = 0; m < 8; ++m) {
#pragma unroll
    for (int cc = 0; cc < 8; ++cc) {
      const int k = 8 * m + cc;
#pragma unroll
      for (int r = 0; r < 4; ++r) {
        const float2 y = ysh[r][k];   // full-wave broadcast
        Gr[cc][r] = fmaf(y.x, wr, Gr[cc][r]);
        Gr[cc][r] = fmaf(-y.y, wi, Gr[cc][r]);
        if (cc != 0 && cc != 4) {
          Gi[cc][r] = fmaf(y.x, wi, Gi[cc][r]);
          Gi[cc][r] = fmaf(y.y, wr, Gi[cc][r]);
        }
      }
      rotm(wr, wi, stepr, stepi);
    }
  }
  const float KK = 0.7071067811865476f;
  const float sgn = (tl & 1) ? -1.f : 1.f;   // (-1)^t, 512j even
#pragma unroll
  for (int r = 0; r < 4; ++r) {
    const float Ae = (Gr[0][r] + Gr[2][r]) + (Gr[4][r] + Gr[6][r]);
    const float Ao = (Gr[1][r] + Gr[3][r]) + (Gr[5][r] + Gr[7][r]);
    const float A2 = (Gr[0][r] - Gr[2][r]) + (Gr[4][r] - Gr[6][r]);
    const float B2 = (Gi[1][r] - Gi[3][r]) + (Gi[5][r] - Gi[7][r]);
    const float P  = Gr[0][r] - Gr[4][r];
    const float Qr = (Gr[1][r] - Gr[3][r]) - (Gr[5][r] - Gr[7][r]);
    const float R  = Gi[6][r] - Gi[2][r];
    const float Qi = (Gi[5][r] - Gi[1][r]) + (Gi[7][r] - Gi[3][r]);
    const float U = P + R, V = P - R;
    const float W1 = KK * (Qr + Qi), W2 = KK * (Qr - Qi);
    float* op = out + (size_t)(row0 + r) * NT + tl;
    op[0]    = sgn * (Ae + Ao);
    op[512]  = sgn * (U + W1);
    op[1024] = sgn * (A2 - B2);
    op[1536] = sgn * (V - W2);
    op[2048] = sgn * (Ae - Ao);
    op[2560] = sgn * (U - W1);
    op[3072] = sgn * (A2 + B2);
    op[3584] = sgn * (V + W2);
  }
}

extern "C" void kernel_launch(void* const* d_in, const int* in_sizes, int n_in,
                              void* d_out, int out_size, void* d_ws, size_t ws_size,
                              hipStream_t stream) {
  const float* x      = (const float*)d_in[0];
  const float* w_real = (const float*)d_in[1];
  const float* w_imag = (const float*)d_in[2];
  float* out = (float*)d_out;

  const size_t MB = (size_t)ROWS * MODES * sizeof(float2);  // 1 MiB units
  int S = 16;
  while (S > 4 && (size_t)(S + 4) * MB > ws_size) S >>= 1;

  char* wsp = (char*)d_ws;
  float2* xfp  = (float2*)wsp;                    // S MB
  float2* xf_t = (float2*)(wsp + (size_t)S * MB); // 1 MB
  float2* yf_t = (float2*)(wsp + (size_t)(S + 1) * MB);
  float*  wrt  = (float*)(wsp + (size_t)(S + 2) * MB);
  float*  wit  = (float*)(wsp + (size_t)(S + 3) * MB);

  cft_kernel<<<64 * S, 256, 0, stream>>>(x, xfp, S);
  wt_reduce_kernel<<<384, 256, 0, stream>>>(w_real, w_imag, wrt, wit,
                                            (const float4*)xfp, xf_t, S);
  mix_kernel<<<128, 256, 0, stream>>>(wrt, wit, xf_t, yf_t);
  icft_kernel<<<1024, 256, 0, stream>>>(yf_t, out);
}

// Round 5
// 49.661 us; speedup vs baseline: 3.0167x; 1.0591x over previous
//
#include <hip/hip_runtime.h>
#include <math.h>

#define NT 4096
#define MODES 64
#define ROWS 2048       // B*Ci == B*Co
#define TWO_PI 6.283185307179586f
#define PI_F 3.14159265358979f

static __device__ __forceinline__ void rotm(float& wr, float& wi, float sr, float si) {
  float nr = fmaf(wr, sr, -wi * si);
  float ni = fmaf(wr, si,  wi * sr);
  wr = nr; wi = ni;
}

// ---------------------------------------------------------------------------
// K1 fused:
//  blocks [0, 64*S): 8-fold CFT partials -> xfp[ts][rowblk(64)][k(64)][rl(32)]
//  blocks [64*S, 64*S+128): w transpose -> w_t[k][i*64+o]
// CFT: xf[row,k] = (1/4096) sum_t x[row,t] e^{-2pi i k t/4096}
//  Fold t = tl + 512 j (j=0..7): s_c(tl) = E_c + e^{-i pi c/4} O_c, c = k mod 8.
//  Thread: k in {k0,k0+16,k0+32,k0+48}, 2 rows; 32 rows/block.
//  Inner loop reads float2 (tl even/odd pair) -> half the LDS instructions.
// ---------------------------------------------------------------------------
__global__ __launch_bounds__(256) void cft_fused_kernel(
    const float* __restrict__ x, float2* __restrict__ xfp,
    const float* __restrict__ w_real, const float* __restrict__ w_imag,
    float* __restrict__ wrt, float* __restrict__ wit, int S) {
  __shared__ __align__(16) char smem[33280];
  const int tid = threadIdx.x;
  const int nCft = 64 * S;

  if ((int)blockIdx.x >= nCft) {
    // ---- w transpose: treat w as A[4096][64]; 64x64 LDS-tiled transpose ----
    float (*tile)[65] = (float (*)[65])smem;
    const int bx = (int)blockIdx.x - nCft;
    const int sel = bx >> 6;
    const int io0 = (bx & 63) * 64;
    const float* __restrict__ src = sel ? w_imag : w_real;
    float* __restrict__ dst = sel ? wit : wrt;
#pragma unroll
    for (int j = 0; j < 4; ++j) {
      const int idx = tid + j * 256;
      const int r = idx >> 4;
      const int kq = idx & 15;
      float4 v = ((const float4*)src)[(size_t)(io0 + r) * 16 + kq];
      tile[r][4 * kq + 0] = v.x; tile[r][4 * kq + 1] = v.y;
      tile[r][4 * kq + 2] = v.z; tile[r][4 * kq + 3] = v.w;
    }
    __syncthreads();
#pragma unroll
    for (int j = 0; j < 16; ++j) {
      const int idx = tid + j * 256;
      const int k = idx >> 6;
      const int r = idx & 63;
      dst[(size_t)k * 4096 + io0 + r] = tile[r][k];
    }
    return;
  }

  // ---- CFT ----
  float4* xs4 = (float4*)smem;      // [row(32)][j(8)][tlf4(8)], row stride 65 float4
  const float* xsf = (const float*)smem;
  const int k0 = tid & 15;
  const int rg = tid >> 4;          // rows rg*2, rg*2+1
  const int C = 512 / S;            // tl per split
  const int rowblk = (int)blockIdx.x / S;
  const int ts = (int)blockIdx.x % S;
  const int row0 = rowblk * 32;

  const int c4 = k0 & 3;
  const float p  = (c4 & 1) ? -1.f : 1.f;
  const float qc = (c4 == 0) ? 1.f : ((c4 == 2) ? -1.f : 0.f);
  const float rc = (c4 == 1) ? -1.f : ((c4 == 3) ? 1.f : 0.f);
  const int c8 = k0 & 7;
  float Aw, Bw;   // e^{-i pi c/4}
  sincosf(-PI_F * (float)c8 * 0.25f, &Bw, &Aw);

  float st2r[4], st2i[4];           // step^2 = e^{-2pi i (2k)/4096}
#pragma unroll
  for (int q = 0; q < 4; ++q) {
    const int k = k0 + 16 * q;
    sincosf(-TWO_PI * (float)(2 * k) / (float)NT, &st2i[q], &st2r[q]);
  }

  float ar[2][4] = {{0.f,0.f,0.f,0.f},{0.f,0.f,0.f,0.f}};
  float ai[2][4] = {{0.f,0.f,0.f,0.f},{0.f,0.f,0.f,0.f}};

  const float4* __restrict__ xg4 = (const float4*)x;
  const float2* bp0 = (const float2*)(xsf + (rg * 2 + 0) * 260);
  const float2* bp1 = (const float2*)(xsf + (rg * 2 + 1) * 260);

  for (int sub = 0; sub < C / 32; ++sub) {
    const int tl0 = ts * C + sub * 32;
    __syncthreads();
    // stage 32 rows x 8 j x 32 tl = 2048 float4; 8 per thread, coalesced.
#pragma unroll
    for (int it = 0; it < 8; ++it) {
      const int idx = tid + it * 256;
      const int tlf = idx & 7;
      const int j = (idx >> 3) & 7;
      const int row = idx >> 6;
      xs4[row * 65 + j * 8 + tlf] =
          xg4[(size_t)(row0 + row) * (NT / 4) + j * 128 + (tl0 >> 2) + tlf];
    }
    __syncthreads();
    // exact integer-phase seeds: chain A at tl0 (even tl), B at tl0+1 (odd)
    float wAr[4], wAi[4], wBr[4], wBi[4];
#pragma unroll
    for (int q = 0; q < 4; ++q) {
      const int k = k0 + 16 * q;
      const int phA = (k * tl0) & (NT - 1);
      const int phB = (k * (tl0 + 1)) & (NT - 1);
      sincosf(-TWO_PI * (float)phA / (float)NT, &wAi[q], &wAr[q]);
      sincosf(-TWO_PI * (float)phB / (float)NT, &wBi[q], &wBr[q]);
    }
#pragma unroll 2
    for (int tt = 0; tt < 16; ++tt) {
      float2 v0[8], v1[8];
#pragma unroll
      for (int j = 0; j < 8; ++j) {
        v0[j] = bp0[j * 16 + tt];
        v1[j] = bp1[j * 16 + tt];
      }
#pragma unroll
      for (int par = 0; par < 2; ++par) {
        const float* wrp = par ? wBr : wAr;
        const float* wip = par ? wBi : wAi;
#pragma unroll
        for (int rr = 0; rr < 2; ++rr) {
          const float2* v = rr ? v1 : v0;
          const float x0 = par ? v[0].y : v[0].x;
          const float x1 = par ? v[1].y : v[1].x;
          const float x2 = par ? v[2].y : v[2].x;
          const float x3 = par ? v[3].y : v[3].x;
          const float x4 = par ? v[4].y : v[4].x;
          const float x5 = par ? v[5].y : v[5].x;
          const float x6 = par ? v[6].y : v[6].x;
          const float x7 = par ? v[7].y : v[7].x;
          const float ue = fmaf(p, x4, x0), ve = fmaf(p, x6, x2);
          const float Er = fmaf(qc, ve, ue), Ei = rc * ve;
          const float uo = fmaf(p, x5, x1), vo = fmaf(p, x7, x3);
          const float Or_ = fmaf(qc, vo, uo), Oi_ = rc * vo;
          float sr = fmaf(Aw, Or_, Er); sr = fmaf(-Bw, Oi_, sr);
          float si = fmaf(Aw, Oi_, Ei); si = fmaf( Bw, Or_, si);
#pragma unroll
          for (int q = 0; q < 4; ++q) {
            ar[rr][q] = fmaf(sr, wrp[q], ar[rr][q]);
            ar[rr][q] = fmaf(-si, wip[q], ar[rr][q]);
            ai[rr][q] = fmaf(sr, wip[q], ai[rr][q]);
            ai[rr][q] = fmaf(si, wrp[q], ai[rr][q]);
          }
        }
      }
#pragma unroll
      for (int q = 0; q < 4; ++q) {
        rotm(wAr[q], wAi[q], st2r[q], st2i[q]);
        rotm(wBr[q], wBi[q], st2r[q], st2i[q]);
      }
    }
  }
  const float dt = 1.0f / (float)NT;
  const size_t base = ((size_t)ts * 64 + rowblk) * 64;
#pragma unroll
  for (int rr = 0; rr < 2; ++rr) {
    const int rl = rg * 2 + rr;
#pragma unroll
    for (int q = 0; q < 4; ++q) {
      xfp[(base + k0 + 16 * q) * 32 + rl] =
          make_float2(ar[rr][q] * dt, ai[rr][q] * dt);
    }
  }
}

// ---------------------------------------------------------------------------
// K2: sum the S partials (coalesced) + spectral mix from LDS.
//   yf[b,o,k] = sum_i xf[b,i,k] * W[i,o,k]
// grid = 512: k = bx&63, bq = bx>>6 (4 b's = 256 rows each).
// ---------------------------------------------------------------------------
__global__ __launch_bounds__(256) void mix_kernel(
    const float* __restrict__ wrt, const float* __restrict__ wit,
    const float2* __restrict__ xfp, float2* __restrict__ yf_t, int S) {
  __shared__ float2 wsc[4096];
  __shared__ float2 xsh[256];
  const int k = blockIdx.x & 63;
  const int bq = blockIdx.x >> 6;
  const int tid = threadIdx.x;
#pragma unroll
  for (int j = 0; j < 4; ++j) {
    const int idx = tid + 256 * j;
    float4 vr = ((const float4*)(wrt + (size_t)k * 4096))[idx];
    float4 vi = ((const float4*)(wit + (size_t)k * 4096))[idx];
    wsc[4 * idx + 0] = make_float2(vr.x, vi.x);
    wsc[4 * idx + 1] = make_float2(vr.y, vi.y);
    wsc[4 * idx + 2] = make_float2(vr.z, vi.z);
    wsc[4 * idx + 3] = make_float2(vr.w, vi.w);
  }
  {
    const int R = bq * 256 + tid;        // global row = b*64 + i
    const int rowblk = R >> 5;
    const int rl = R & 31;
    float2 acc = make_float2(0.f, 0.f);
    for (int s = 0; s < S; ++s) {
      float2 v = xfp[(((size_t)s * 64 + rowblk) * 64 + k) * 32 + rl];
      acc.x += v.x; acc.y += v.y;
    }
    xsh[tid] = acc;
  }
  __syncthreads();
  const int o = tid & 63;
  const int bl = tid >> 6;
  float accr = 0.f, acci = 0.f;
#pragma unroll 8
  for (int i = 0; i < 64; ++i) {
    const float2 xv = xsh[bl * 64 + i];  // broadcast (bl uniform per wave)
    const float2 w = wsc[i * 64 + o];
    accr = fmaf(xv.x, w.x, accr); accr = fmaf(-xv.y, w.y, accr);
    acci = fmaf(xv.x, w.y, acci); acci = fmaf( xv.y, w.x, acci);
  }
  yf_t[(size_t)k * ROWS + bq * 256 + bl * 64 + o] = make_float2(accr, acci);
}

// ---------------------------------------------------------------------------
// K3: 8-fold ICFT with fftshift pairing (unchanged from round 4):
//   out[row,t] = (-1)^t Re sum_k yf[row,k] e^{+2pi i k t/4096}
// grid = 1024: 512 rowgroups (4 rows) x 2 tl-chunks (256 each).
// ---------------------------------------------------------------------------
__global__ __launch_bounds__(256) void icft_kernel(const float2* __restrict__ yf_t,
                                                   float* __restrict__ out) {
  __shared__ float2 ysh[4][66];
  const int rgrp = blockIdx.x >> 1;
  const int tc = blockIdx.x & 1;
  const int row0 = rgrp * 4;
  const int tid = threadIdx.x;
  {
    const int k = tid >> 2;
    const int r = tid & 3;
    ysh[r][k] = yf_t[(size_t)k * ROWS + row0 + r];
  }
  __syncthreads();
  const int tl = tc * 256 + tid;
  float stepr, stepi;
  sincosf(TWO_PI * (float)tl / (float)NT, &stepi, &stepr);
  float wr = 1.f, wi = 0.f;
  float Gr[8][4] = {{0.f}};
  float Gi[8][4] = {{0.f}};   // [0],[4] unused -> dead after unroll
  for (int m = 0; m < 8; ++m) {
#pragma unroll
    for (int cc = 0; cc < 8; ++cc) {
      const int k = 8 * m + cc;
#pragma unroll
      for (int r = 0; r < 4; ++r) {
        const float2 y = ysh[r][k];   // full-wave broadcast
        Gr[cc][r] = fmaf(y.x, wr, Gr[cc][r]);
        Gr[cc][r] = fmaf(-y.y, wi, Gr[cc][r]);
        if (cc != 0 && cc != 4) {
          Gi[cc][r] = fmaf(y.x, wi, Gi[cc][r]);
          Gi[cc][r] = fmaf(y.y, wr, Gi[cc][r]);
        }
      }
      rotm(wr, wi, stepr, stepi);
    }
  }
  const float KK = 0.7071067811865476f;
  const float sgn = (tl & 1) ? -1.f : 1.f;
#pragma unroll
  for (int r = 0; r < 4; ++r) {
    const float Ae = (Gr[0][r] + Gr[2][r]) + (Gr[4][r] + Gr[6][r]);
    const float Ao = (Gr[1][r] + Gr[3][r]) + (Gr[5][r] + Gr[7][r]);
    const float A2 = (Gr[0][r] - Gr[2][r]) + (Gr[4][r] - Gr[6][r]);
    const float B2 = (Gi[1][r] - Gi[3][r]) + (Gi[5][r] - Gi[7][r]);
    const float P  = Gr[0][r] - Gr[4][r];
    const float Qr = (Gr[1][r] - Gr[3][r]) - (Gr[5][r] - Gr[7][r]);
    const float R  = Gi[6][r] - Gi[2][r];
    const float Qi = (Gi[5][r] - Gi[1][r]) + (Gi[7][r] - Gi[3][r]);
    const float U = P + R, V = P - R;
    const float W1 = KK * (Qr + Qi), W2 = KK * (Qr - Qi);
    float* op = out + (size_t)(row0 + r) * NT + tl;
    op[0]    = sgn * (Ae + Ao);
    op[512]  = sgn * (U + W1);
    op[1024] = sgn * (A2 - B2);
    op[1536] = sgn * (V - W2);
    op[2048] = sgn * (Ae - Ao);
    op[2560] = sgn * (U - W1);
    op[3072] = sgn * (A2 + B2);
    op[3584] = sgn * (V + W2);
  }
}

extern "C" void kernel_launch(void* const* d_in, const int* in_sizes, int n_in,
                              void* d_out, int out_size, void* d_ws, size_t ws_size,
                              hipStream_t stream) {
  const float* x      = (const float*)d_in[0];
  const float* w_real = (const float*)d_in[1];
  const float* w_imag = (const float*)d_in[2];
  float* out = (float*)d_out;

  const size_t MB = (size_t)ROWS * MODES * sizeof(float2);  // 1 MiB units
  int S = 16;
  while (S > 4 && (size_t)(S + 4) * MB > ws_size) S >>= 1;

  char* wsp = (char*)d_ws;
  float2* xfp  = (float2*)wsp;                        // S MB: [ts][rowblk][k][rl]
  float2* yf_t = (float2*)(wsp + (size_t)S * MB);     // 2 MB: [k][row]
  float*  wrt  = (float*)(wsp + (size_t)(S + 2) * MB);
  float*  wit  = (float*)(wsp + (size_t)(S + 3) * MB);

  cft_fused_kernel<<<64 * S + 128, 256, 0, stream>>>(x, xfp, w_real, w_imag,
                                                     wrt, wit, S);
  mix_kernel<<<512, 256, 0, stream>>>(wrt, wit, xfp, yf_t, S);
  icft_kernel<<<1024, 256, 0, stream>>>(yf_t, out);
}

// Round 6
// 47.632 us; speedup vs baseline: 3.1452x; 1.0426x over previous
//
#include <hip/hip_runtime.h>
#include <math.h>

#define NT 4096
#define MODES 64
#define ROWS 2048       // B*Ci == B*Co
#define TWO_PI 6.283185307179586f
#define PI_F 3.14159265358979f

static __device__ __forceinline__ void rotm(float& wr, float& wi, float sr, float si) {
  float nr = fmaf(wr, sr, -wi * si);
  float ni = fmaf(wr, si,  wi * sr);
  wr = nr; wi = ni;
}

// ---------------------------------------------------------------------------
// K1 fused:
//  blocks [0, 64*S): 8-fold CFT partials -> xfp[ts][rowblk(64)][k(64)][rl(32)]
//  blocks [64*S, 64*S+128): w transpose -> w_t[k][i*64+o]
// CFT: xf[row,k] = (1/4096) sum_t x[row,t] e^{-2pi i k t/4096}
//  Fold t = tl + 512 j (j=0..7): s_c(tl) = E_c + e^{-i pi c/4} O_c, c = k mod 8.
//  Thread: k in {k0+8q, q=0..7} (ALL share class c8=k0 -> one fold serves 8 k),
//  1 row; 32 rows/block. Twiddles from an exact-integer-phase LDS table
//  (built per 16-tl chunk) instead of rotation chains.
// ---------------------------------------------------------------------------
__global__ __launch_bounds__(256) void cft_fused_kernel(
    const float* __restrict__ x, float2* __restrict__ xfp,
    const float* __restrict__ w_real, const float* __restrict__ w_imag,
    float* __restrict__ wrt, float* __restrict__ wit, int S) {
  __shared__ __align__(16) char smem[25344];
  const int tid = threadIdx.x;
  const int nCft = 64 * S;

  if ((int)blockIdx.x >= nCft) {
    // ---- w transpose: treat w as A[4096][64]; 64x64 LDS-tiled transpose ----
    float (*tile)[65] = (float (*)[65])smem;
    const int bx = (int)blockIdx.x - nCft;
    const int sel = bx >> 6;
    const int io0 = (bx & 63) * 64;
    const float* __restrict__ src = sel ? w_imag : w_real;
    float* __restrict__ dst = sel ? wit : wrt;
#pragma unroll
    for (int j = 0; j < 4; ++j) {
      const int idx = tid + j * 256;
      const int r = idx >> 4;
      const int kq = idx & 15;
      float4 v = ((const float4*)src)[(size_t)(io0 + r) * 16 + kq];
      tile[r][4 * kq + 0] = v.x; tile[r][4 * kq + 1] = v.y;
      tile[r][4 * kq + 2] = v.z; tile[r][4 * kq + 3] = v.w;
    }
    __syncthreads();
#pragma unroll
    for (int j = 0; j < 16; ++j) {
      const int idx = tid + j * 256;
      const int k = idx >> 6;
      const int r = idx & 63;
      dst[(size_t)k * 4096 + io0 + r] = tile[r][k];
    }
    return;
  }

  // ---- CFT ----
  // LDS: x-stage [32 rows][8 j][16 tl] floats, row stride 132 (16B-aligned,
  //      rows land on distinct banks); tw table [16 tl][64 k] complex, row
  //      stride 66 float2.
  float* xsf = (float*)smem;                    // 16896 B
  float2* tws = (float2*)(smem + 16896);        // 8448 B
  const int k0 = tid & 7;          // class c8 = k0, k = k0 + 8q
  const int rg = tid >> 3;         // row 0..31
  const int C = 512 / S;           // tl per split
  const int rowblk = (int)blockIdx.x / S;
  const int ts = (int)blockIdx.x % S;
  const int row0 = rowblk * 32;

  const int c4 = k0 & 3;
  const float p  = (c4 & 1) ? -1.f : 1.f;
  const float qc = (c4 == 0) ? 1.f : ((c4 == 2) ? -1.f : 0.f);
  const float rc = (c4 == 1) ? -1.f : ((c4 == 3) ? 1.f : 0.f);
  float Aw, Bw;   // e^{-i pi c8/4}
  sincosf(-PI_F * (float)k0 * 0.25f, &Bw, &Aw);

  float ar[8] = {0.f,0.f,0.f,0.f,0.f,0.f,0.f,0.f};
  float ai[8] = {0.f,0.f,0.f,0.f,0.f,0.f,0.f,0.f};

  const float4* __restrict__ xg4 = (const float4*)x;
  const float2* bp = (const float2*)(xsf + rg * 132);

  for (int sub = 0; sub < C / 16; ++sub) {
    const int tl0 = ts * C + sub * 16;
    __syncthreads();
    // stage 32 rows x 8 j x 16 tl = 1024 float4-quarters; 4 float4 per thread.
#pragma unroll
    for (int it = 0; it < 4; ++it) {
      const int idx = tid + it * 256;
      const int tlf = idx & 3;
      const int j = (idx >> 2) & 7;
      const int row = idx >> 5;
      ((float4*)xsf)[row * 33 + j * 4 + tlf] =
          xg4[(size_t)(row0 + row) * (NT / 4) + j * 128 + (tl0 >> 2) + tlf];
    }
    // twiddle table: tw[tl][k] = e^{-2pi i ((k*(tl0+tl)) mod 4096)/4096}
#pragma unroll
    for (int it = 0; it < 4; ++it) {
      const int e = tid + it * 256;
      const int tl = e >> 6;
      const int k = e & 63;
      const int ph = (k * (tl0 + tl)) & (NT - 1);
      float swr, swi;
      sincosf(-TWO_PI * (float)ph / (float)NT, &swi, &swr);
      tws[tl * 66 + k] = make_float2(swr, swi);
    }
    __syncthreads();
#pragma unroll 2
    for (int tt = 0; tt < 8; ++tt) {
      float2 v[8];
#pragma unroll
      for (int j = 0; j < 8; ++j) v[j] = bp[j * 8 + tt];
#pragma unroll
      for (int par = 0; par < 2; ++par) {
        const int tl = 2 * tt + par;
        const float x0 = par ? v[0].y : v[0].x;
        const float x1 = par ? v[1].y : v[1].x;
        const float x2 = par ? v[2].y : v[2].x;
        const float x3 = par ? v[3].y : v[3].x;
        const float x4 = par ? v[4].y : v[4].x;
        const float x5 = par ? v[5].y : v[5].x;
        const float x6 = par ? v[6].y : v[6].x;
        const float x7 = par ? v[7].y : v[7].x;
        const float ue = fmaf(p, x4, x0), ve = fmaf(p, x6, x2);
        const float Er = fmaf(qc, ve, ue), Ei = rc * ve;
        const float uo = fmaf(p, x5, x1), vo = fmaf(p, x7, x3);
        const float Or_ = fmaf(qc, vo, uo), Oi_ = rc * vo;
        float sr = fmaf(Aw, Or_, Er); sr = fmaf(-Bw, Oi_, sr);
        float si = fmaf(Aw, Oi_, Ei); si = fmaf( Bw, Or_, si);
#pragma unroll
        for (int q = 0; q < 8; ++q) {
          const float2 w = tws[tl * 66 + k0 + 8 * q];  // broadcast over rg
          ar[q] = fmaf(sr, w.x, ar[q]); ar[q] = fmaf(-si, w.y, ar[q]);
          ai[q] = fmaf(sr, w.y, ai[q]); ai[q] = fmaf( si, w.x, ai[q]);
        }
      }
    }
  }
  const float dt = 1.0f / (float)NT;
  const size_t base = ((size_t)ts * 64 + rowblk) * 64;
#pragma unroll
  for (int q = 0; q < 8; ++q) {
    xfp[(base + k0 + 8 * q) * 32 + rg] = make_float2(ar[q] * dt, ai[q] * dt);
  }
}

// ---------------------------------------------------------------------------
// K2: sum the S partials (coalesced) + spectral mix from LDS.
//   yf[b,o,k] = sum_i xf[b,i,k] * W[i,o,k]
// grid = 512: k = bx&63, bq = bx>>6 (4 b's = 256 rows each).
// ---------------------------------------------------------------------------
__global__ __launch_bounds__(256) void mix_kernel(
    const float* __restrict__ wrt, const float* __restrict__ wit,
    const float2* __restrict__ xfp, float2* __restrict__ yf_t, int S) {
  __shared__ float2 wsc[4096];
  __shared__ float2 xsh[256];
  const int k = blockIdx.x & 63;
  const int bq = blockIdx.x >> 6;
  const int tid = threadIdx.x;
#pragma unroll
  for (int j = 0; j < 4; ++j) {
    const int idx = tid + 256 * j;
    float4 vr = ((const float4*)(wrt + (size_t)k * 4096))[idx];
    float4 vi = ((const float4*)(wit + (size_t)k * 4096))[idx];
    wsc[4 * idx + 0] = make_float2(vr.x, vi.x);
    wsc[4 * idx + 1] = make_float2(vr.y, vi.y);
    wsc[4 * idx + 2] = make_float2(vr.z, vi.z);
    wsc[4 * idx + 3] = make_float2(vr.w, vi.w);
  }
  {
    const int R = bq * 256 + tid;        // global row = b*64 + i
    const int rowblk = R >> 5;
    const int rl = R & 31;
    float2 acc = make_float2(0.f, 0.f);
    for (int s = 0; s < S; ++s) {
      float2 v = xfp[(((size_t)s * 64 + rowblk) * 64 + k) * 32 + rl];
      acc.x += v.x; acc.y += v.y;
    }
    xsh[tid] = acc;
  }
  __syncthreads();
  const int o = tid & 63;
  const int bl = tid >> 6;
  float accr = 0.f, acci = 0.f;
#pragma unroll 8
  for (int i = 0; i < 64; ++i) {
    const float2 xv = xsh[bl * 64 + i];  // broadcast (bl uniform per wave)
    const float2 w = wsc[i * 64 + o];
    accr = fmaf(xv.x, w.x, accr); accr = fmaf(-xv.y, w.y, accr);
    acci = fmaf(xv.x, w.y, acci); acci = fmaf( xv.y, w.x, acci);
  }
  yf_t[(size_t)k * ROWS + bq * 256 + bl * 64 + o] = make_float2(accr, acci);
}

// ---------------------------------------------------------------------------
// K3: 8-fold ICFT with fftshift pairing (unchanged):
//   out[row,t] = (-1)^t Re sum_k yf[row,k] e^{+2pi i k t/4096}
// grid = 1024: 512 rowgroups (4 rows) x 2 tl-chunks (256 each).
// ---------------------------------------------------------------------------
__global__ __launch_bounds__(256) void icft_kernel(const float2* __restrict__ yf_t,
                                                   float* __restrict__ out) {
  __shared__ float2 ysh[4][66];
  const int rgrp = blockIdx.x >> 1;
  const int tc = blockIdx.x & 1;
  const int row0 = rgrp * 4;
  const int tid = threadIdx.x;
  {
    const int k = tid >> 2;
    const int r = tid & 3;
    ysh[r][k] = yf_t[(size_t)k * ROWS + row0 + r];
  }
  __syncthreads();
  const int tl = tc * 256 + tid;
  float stepr, stepi;
  sincosf(TWO_PI * (float)tl / (float)NT, &stepi, &stepr);
  float wr = 1.f, wi = 0.f;
  float Gr[8][4] = {{0.f}};
  float Gi[8][4] = {{0.f}};   // [0],[4] unused -> dead after unroll
  for (int m = 0; m < 8; ++m) {
#pragma unroll
    for (int cc = 0; cc < 8; ++cc) {
      const int k = 8 * m + cc;
#pragma unroll
      for (int r = 0; r < 4; ++r) {
        const float2 y = ysh[r][k];   // full-wave broadcast
        Gr[cc][r] = fmaf(y.x, wr, Gr[cc][r]);
        Gr[cc][r] = fmaf(-y.y, wi, Gr[cc][r]);
        if (cc != 0 && cc != 4) {
          Gi[cc][r] = fmaf(y.x, wi, Gi[cc][r]);
          Gi[cc][r] = fmaf(y.y, wr, Gi[cc][r]);
        }
      }
      rotm(wr, wi, stepr, stepi);
    }
  }
  const float KK = 0.7071067811865476f;
  const float sgn = (tl & 1) ? -1.f : 1.f;
#pragma unroll
  for (int r = 0; r < 4; ++r) {
    const float Ae = (Gr[0][r] + Gr[2][r]) + (Gr[4][r] + Gr[6][r]);
    const float Ao = (Gr[1][r] + Gr[3][r]) + (Gr[5][r] + Gr[7][r]);
    const float A2 = (Gr[0][r] - Gr[2][r]) + (Gr[4][r] - Gr[6][r]);
    const float B2 = (Gi[1][r] - Gi[3][r]) + (Gi[5][r] - Gi[7][r]);
    const float P  = Gr[0][r] - Gr[4][r];
    const float Qr = (Gr[1][r] - Gr[3][r]) - (Gr[5][r] - Gr[7][r]);
    const float R  = Gi[6][r] - Gi[2][r];
    const float Qi = (Gi[5][r] - Gi[1][r]) + (Gi[7][r] - Gi[3][r]);
    const float U = P + R, V = P - R;
    const float W1 = KK * (Qr + Qi), W2 = KK * (Qr - Qi);
    float* op = out + (size_t)(row0 + r) * NT + tl;
    op[0]    = sgn * (Ae + Ao);
    op[512]  = sgn * (U + W1);
    op[1024] = sgn * (A2 - B2);
    op[1536] = sgn * (V - W2);
    op[2048] = sgn * (Ae - Ao);
    op[2560] = sgn * (U - W1);
    op[3072] = sgn * (A2 + B2);
    op[3584] = sgn * (V + W2);
  }
}

extern "C" void kernel_launch(void* const* d_in, const int* in_sizes, int n_in,
                              void* d_out, int out_size, void* d_ws, size_t ws_size,
                              hipStream_t stream) {
  const float* x      = (const float*)d_in[0];
  const float* w_real = (const float*)d_in[1];
  const float* w_imag = (const float*)d_in[2];
  float* out = (float*)d_out;

  const size_t MB = (size_t)ROWS * MODES * sizeof(float2);  // 1 MiB units
  int S = 16;
  while (S > 4 && (size_t)(S + 4) * MB > ws_size) S >>= 1;

  char* wsp = (char*)d_ws;
  float2* xfp  = (float2*)wsp;                        // S MB: [ts][rowblk][k][rl]
  float2* yf_t = (float2*)(wsp + (size_t)S * MB);     // 2 MB: [k][row]
  float*  wrt  = (float*)(wsp + (size_t)(S + 2) * MB);
  float*  wit  = (float*)(wsp + (size_t)(S + 3) * MB);

  cft_fused_kernel<<<64 * S + 128, 256, 0, stream>>>(x, xfp, w_real, w_imag,
                                                     wrt, wit, S);
  mix_kernel<<<512, 256, 0, stream>>>(wrt, wit, xfp, yf_t, S);
  icft_kernel<<<1024, 256, 0, stream>>>(yf_t, out);
}